// Round 5
// baseline (10733.021 us; speedup 1.0000x reference)
//
#include <hip/hip_runtime.h>
#include <math.h>

#define NNEUR 300          // NN
#define NFEAT 20           // NF
#define NPAD  320          // padded n-dimension
#define MAUGP 336          // 300 r + 20 image + 1 hold + 1 const + 14 pad = 16*21
#define NOUT  50
#define NPMAC 100          // NPM
#define TSTEPS 500
#define BATCH 1024
#define NWAVE 16
#define MCHUNK 21          // m-rows per wave
#define RROWS 17           // rows held in registers (17*5 = 85 VGPRs, named scalars)
#define LROWS 4            // rows held in LDS

// Augmented transposed weight matrix W[m][n], n padded to 320:
//   m in [0,300):   W[m][n] = J[n][m]
//   m in [300,320): W[m][n] = I[n][m-300]
//   m == 320:       W[m][n] = S[n]
//   m == 321:       W[m][n] = Bb[n]   (activation fixed at 1)
//   else / n>=300:  0
__global__ void build_w_kernel(const float* __restrict__ J,
                               const float* __restrict__ I,
                               const float* __restrict__ S,
                               const float* __restrict__ Bb,
                               float* __restrict__ W) {
    int e = blockIdx.x * 256 + threadIdx.x;
    if (e >= MAUGP * NPAD) return;
    int m = e / NPAD, n = e % NPAD;
    float v = 0.0f;
    if (n < NNEUR) {
        if (m < NNEUR)                   v = J[n * NNEUR + m];
        else if (m < NNEUR + NFEAT)      v = I[n * NFEAT + (m - NNEUR)];
        else if (m == NNEUR + NFEAT)     v = S[n];
        else if (m == NNEUR + NFEAT + 1) v = Bb[n];
    }
    W[e] = v;
}

// Apply macro F to each register-row index 0..16.
#define ROWS_ITER(F) F(0) F(1) F(2) F(3) F(4) F(5) F(6) F(7) F(8) \
                     F(9) F(10) F(11) F(12) F(13) F(14) F(15) F(16)

// Persistent RNN: 256 blocks x 1024 threads (16 waves), 1 block/CU (LDS-limited).
// Weights for 17 of 21 rows/wave live in NAMED SCALAR floats pinned via asm
// (rounds 3/4: asm pins on float4-array elements broke SROA -> the array went
// to scratch -> 28 GB HBM spill traffic; named scalars are SROA-proof).
// waves_per_eu(4,4): LDS forces 1 block/CU = 4 waves/EU; declare it so the
// allocator budget is 128 VGPRs, not the 8-wave default of 64.
__global__ void
__attribute__((amdgpu_flat_work_group_size(1024, 1024), amdgpu_waves_per_eu(4, 4)))
rnn_kernel(
    const float* __restrict__ W,      // [MAUGP][NPAD]
    const float* __restrict__ data,   // [T][21][B]
    const float* __restrict__ x0,     // [NNEUR]
    const float* __restrict__ fcw,    // [NOUT][NPMAC]
    const float* __restrict__ fcb,    // [NOUT]
    float* __restrict__ out)          // [T][B][NOUT]
{
    __shared__ __align__(16) float Wl[NWAVE][LROWS][NPAD];   // 80 KB
    __shared__ __align__(16) float part[8][4][NPAD];         // 40 KB
    __shared__ __align__(16) float raug[MAUGP][4];           // 5.4 KB
    __shared__ __align__(16) float xs[4][NPAD];              // 5 KB
    __shared__ float fcwt[NPMAC][NOUT];                      // 20 KB
    __shared__ float fcbs[NOUT];

    const int tid = threadIdx.x;
    const int wid = tid >> 6;
    const int l   = tid & 63;
    const int b0  = blockIdx.x * 4;
    const int m0  = wid * MCHUNK;

    // ---- init: zero raug, load fc weights ----
    for (int i = tid; i < MAUGP * 4; i += 1024) ((float*)raug)[i] = 0.0f;
    for (int i = tid; i < NPMAC * NOUT; i += 1024) {
        int p = i / NOUT, o = i - p * NOUT;
        fcwt[p][o] = fcw[o * NPMAC + p];
    }
    if (tid < NOUT) fcbs[tid] = fcb[tid];
    __syncthreads();

    for (int i = tid; i < NNEUR; i += 1024) {
        float xv = x0[i];
        float rv = fmaxf(tanhf(xv), 0.0f);
        #pragma unroll
        for (int b = 0; b < 4; ++b) { xs[b][i] = xv; raug[i][b] = rv; }
    }
    if (tid < 4) raug[NNEUR + NFEAT + 1][tid] = 1.0f;   // const row

    // ---- load weight chunk: 17 rows -> named scalar VGPRs, 4 rows -> LDS ----
#define WDECL(i) float wx##i, wy##i, wz##i, ww##i, wv##i;
    ROWS_ITER(WDECL)
#define WLOAD(i) { \
        const float4 t4_ = *reinterpret_cast<const float4*>( \
            &W[(size_t)(m0 + (i)) * NPAD + 4 * l]); \
        wx##i = t4_.x; wy##i = t4_.y; wz##i = t4_.z; ww##i = t4_.w; \
        wv##i = W[(size_t)(m0 + (i)) * NPAD + 256 + l]; }
    ROWS_ITER(WLOAD)
#define WPIN(i) asm volatile("" : "+v"(wx##i), "+v"(wy##i), "+v"(wz##i), \
                                  "+v"(ww##i), "+v"(wv##i));
    ROWS_ITER(WPIN)

    #pragma unroll
    for (int i = 0; i < LROWS; ++i) {
        *reinterpret_cast<float4*>(&Wl[wid][i][4 * l]) =
            *reinterpret_cast<const float4*>(&W[(size_t)(m0 + RROWS + i) * NPAD + 4 * l]);
        Wl[wid][i][256 + l] = W[(size_t)(m0 + RROWS + i) * NPAD + 256 + l];
    }

    // prefetch data[t=0] slice (21 rows x 4 batch)
    float4 dstage = make_float4(0.f, 0.f, 0.f, 0.f);
    if (tid < NFEAT + 1)
        dstage = *reinterpret_cast<const float4*>(data + (size_t)tid * BATCH + b0);
    __syncthreads();

    for (int t = 0; t < TSTEPS; ++t) {
        // ---- Phase A: commit data[t], prefetch data[t+1] ----
        if (tid < NFEAT + 1) {
            *reinterpret_cast<float4*>(&raug[NNEUR + tid][0]) = dstage;
            if (t + 1 < TSTEPS)
                dstage = *reinterpret_cast<const float4*>(
                    data + ((size_t)(t + 1) * (NFEAT + 1) + tid) * BATCH + b0);
        }
        __syncthreads();

        // ---- Phase B: per-wave matvec over its 21-row m-chunk ----
        float a00 = 0.f, a01 = 0.f, a02 = 0.f, a03 = 0.f;
        float a10 = 0.f, a11 = 0.f, a12 = 0.f, a13 = 0.f;
        float a20 = 0.f, a21 = 0.f, a22 = 0.f, a23 = 0.f;
        float a30 = 0.f, a31 = 0.f, a32 = 0.f, a33 = 0.f;
        float t0 = 0.f, t1 = 0.f, t2 = 0.f, t3 = 0.f;

#define WFMA(i) { \
        const float4 rv_ = *reinterpret_cast<const float4*>(&raug[m0 + (i)][0]); \
        a00 += wx##i * rv_.x; a01 += wx##i * rv_.y; a02 += wx##i * rv_.z; a03 += wx##i * rv_.w; \
        a10 += wy##i * rv_.x; a11 += wy##i * rv_.y; a12 += wy##i * rv_.z; a13 += wy##i * rv_.w; \
        a20 += wz##i * rv_.x; a21 += wz##i * rv_.y; a22 += wz##i * rv_.z; a23 += wz##i * rv_.w; \
        a30 += ww##i * rv_.x; a31 += ww##i * rv_.y; a32 += ww##i * rv_.z; a33 += ww##i * rv_.w; \
        t0  += wv##i * rv_.x; t1  += wv##i * rv_.y; t2  += wv##i * rv_.z; t3  += wv##i * rv_.w; }
        ROWS_ITER(WFMA)

        #pragma unroll
        for (int i = 0; i < LROWS; ++i) {
            const float4 rv_ = *reinterpret_cast<const float4*>(&raug[m0 + RROWS + i][0]);
            const float4 wv_ = *reinterpret_cast<const float4*>(&Wl[wid][i][4 * l]);
            const float wlt  = Wl[wid][i][256 + l];
            a00 += wv_.x * rv_.x; a01 += wv_.x * rv_.y; a02 += wv_.x * rv_.z; a03 += wv_.x * rv_.w;
            a10 += wv_.y * rv_.x; a11 += wv_.y * rv_.y; a12 += wv_.y * rv_.z; a13 += wv_.y * rv_.w;
            a20 += wv_.z * rv_.x; a21 += wv_.z * rv_.y; a22 += wv_.z * rv_.z; a23 += wv_.z * rv_.w;
            a30 += wv_.w * rv_.x; a31 += wv_.w * rv_.y; a32 += wv_.w * rv_.z; a33 += wv_.w * rv_.w;
            t0  += wlt  * rv_.x; t1  += wlt  * rv_.y; t2  += wlt  * rv_.z; t3  += wlt  * rv_.w;
        }

        // ---- two-stage partial reduce: waves 0-7 write, 8-15 RMW-add ----
        if (wid < 8) {
            *reinterpret_cast<float4*>(&part[wid][0][4 * l]) = make_float4(a00, a10, a20, a30);
            part[wid][0][256 + l] = t0;
            *reinterpret_cast<float4*>(&part[wid][1][4 * l]) = make_float4(a01, a11, a21, a31);
            part[wid][1][256 + l] = t1;
            *reinterpret_cast<float4*>(&part[wid][2][4 * l]) = make_float4(a02, a12, a22, a32);
            part[wid][2][256 + l] = t2;
            *reinterpret_cast<float4*>(&part[wid][3][4 * l]) = make_float4(a03, a13, a23, a33);
            part[wid][3][256 + l] = t3;
        }
        __syncthreads();
        if (wid >= 8) {
            const int w8 = wid - 8;
            float4 p4;
            p4 = *reinterpret_cast<float4*>(&part[w8][0][4 * l]);
            p4.x += a00; p4.y += a10; p4.z += a20; p4.w += a30;
            *reinterpret_cast<float4*>(&part[w8][0][4 * l]) = p4;
            part[w8][0][256 + l] += t0;
            p4 = *reinterpret_cast<float4*>(&part[w8][1][4 * l]);
            p4.x += a01; p4.y += a11; p4.z += a21; p4.w += a31;
            *reinterpret_cast<float4*>(&part[w8][1][4 * l]) = p4;
            part[w8][1][256 + l] += t1;
            p4 = *reinterpret_cast<float4*>(&part[w8][2][4 * l]);
            p4.x += a02; p4.y += a12; p4.z += a22; p4.w += a32;
            *reinterpret_cast<float4*>(&part[w8][2][4 * l]) = p4;
            part[w8][2][256 + l] += t2;
            p4 = *reinterpret_cast<float4*>(&part[w8][3][4 * l]);
            p4.x += a03; p4.y += a13; p4.z += a23; p4.w += a33;
            *reinterpret_cast<float4*>(&part[w8][3][4 * l]) = p4;
            part[w8][3][256 + l] += t3;
        }
        __syncthreads();

        // ---- Phase C: reduce 8 partials, state update, write r ----
        {
            int b = tid / NPAD;
            int n = tid - b * NPAD;
            if (n < NNEUR) {
                float s = 0.0f;
                #pragma unroll
                for (int w8 = 0; w8 < 8; ++w8) s += part[w8][b][n];
                float xo  = xs[b][n];
                float pre = xo + (s - xo) * 0.1f;     // x + tdx/10
                xs[b][n] = pre;
                raug[n][b] = fmaxf(tanhf(pre), 0.0f);
            }
            if (tid < 256) {                           // items 1024..1279 -> b=3
                int n2 = 64 + tid;
                if (n2 < NNEUR) {
                    float s = 0.0f;
                    #pragma unroll
                    for (int w8 = 0; w8 < 8; ++w8) s += part[w8][3][n2];
                    float xo  = xs[3][n2];
                    float pre = xo + (s - xo) * 0.1f;
                    xs[3][n2] = pre;
                    raug[n2][3] = fmaxf(tanhf(pre), 0.0f);
                }
            }
        }
        __syncthreads();

        // ---- Phase D: y = r[:, :100] @ fcw.T + fcb, 4 threads per (b,o) ----
        if (tid < 800) {
            int pair = tid >> 2, seg = tid & 3;
            int b = pair / NOUT, o = pair - (pair / NOUT) * NOUT;
            int pb = seg * 25;
            float y = 0.0f;
            #pragma unroll 5
            for (int k = 0; k < 25; ++k)
                y += raug[pb + k][b] * fcwt[pb + k][o];
            y += __shfl_down(y, 1, 4);
            y += __shfl_down(y, 2, 4);
            if (seg == 0)
                out[((size_t)t * BATCH + b0 + b) * NOUT + o] = y + fcbs[o];
        }
        // no barrier: D reads raug rows <100; next A writes rows >=300; the
        // A-end barrier orders everything before the next part-write.
    }
}

extern "C" void kernel_launch(void* const* d_in, const int* in_sizes, int n_in,
                              void* d_out, int out_size, void* d_ws, size_t ws_size,
                              hipStream_t stream) {
    const float* data = (const float*)d_in[0];
    const float* J    = (const float*)d_in[1];
    const float* I    = (const float*)d_in[2];
    const float* S    = (const float*)d_in[3];
    const float* Bb   = (const float*)d_in[4];
    const float* x0   = (const float*)d_in[5];
    const float* fcw  = (const float*)d_in[6];
    const float* fcb  = (const float*)d_in[7];
    float* out = (float*)d_out;
    float* W   = (float*)d_ws;   // MAUGP*NPAD*4 = 430,080 bytes

    int wtot = MAUGP * NPAD;
    build_w_kernel<<<(wtot + 255) / 256, 256, 0, stream>>>(J, I, S, Bb, W);
    rnn_kernel<<<256, 1024, 0, stream>>>(W, data, x0, fcw, fcb, out);
}

// Round 6
// 3470.151 us; speedup vs baseline: 3.0930x; 3.0930x over previous
//
#include <hip/hip_runtime.h>
#include <math.h>

#define NNEUR 300          // NN
#define NFEAT 20           // NF
#define NPAD  320          // padded n-dimension
#define MAUGP 336          // 300 r + 20 image + 1 hold + 1 const + 14 pad = 16*21
#define NOUT  50
#define NPMAC 100          // NPM
#define TSTEPS 500
#define BATCH 1024
#define NWAVE 16
#define MCHUNK 21          // m-rows per wave
#define RES   2            // rows resident in registers (plain, under-budget)
#define LROWS 4            // rows held in LDS
#define STRM  15           // rows streamed from L2 (RES+LROWS+STRM == MCHUNK)

// Augmented transposed weight matrix W[m][n], n padded to 320:
//   m in [0,300):   W[m][n] = J[n][m]
//   m in [300,320): W[m][n] = I[n][m-300]
//   m == 320:       W[m][n] = S[n]
//   m == 321:       W[m][n] = Bb[n]   (activation fixed at 1)
//   else / n>=300:  0
__global__ void build_w_kernel(const float* __restrict__ J,
                               const float* __restrict__ I,
                               const float* __restrict__ S,
                               const float* __restrict__ Bb,
                               float* __restrict__ W) {
    int e = blockIdx.x * 256 + threadIdx.x;
    if (e >= MAUGP * NPAD) return;
    int m = e / NPAD, n = e % NPAD;
    float v = 0.0f;
    if (n < NNEUR) {
        if (m < NNEUR)                   v = J[n * NNEUR + m];
        else if (m < NNEUR + NFEAT)      v = I[n * NFEAT + (m - NNEUR)];
        else if (m == NNEUR + NFEAT)     v = S[n];
        else if (m == NNEUR + NFEAT + 1) v = Bb[n];
    }
    W[e] = v;
}

// Persistent RNN: 256 blocks x 1024 threads (16 waves), 1 block/CU (LDS-limited).
// Budget-aware hybrid: rounds 3-5 proved the allocator holds a 64-VGPR budget
// (pins spilled to scratch: +90MB one-time WRITE, +30GB FETCH from 500x
// reloads). Design demand ~62 regs: 2 resident W rows (10), depth-1 stream
// pipeline (10), 20 accumulators, misc. 15 rows/wave stream from L2
// (~307 KB/CU/step, W is L2-resident), 4 rows from LDS.
__global__ __launch_bounds__(1024, 4) void rnn_kernel(
    const float* __restrict__ W,      // [MAUGP][NPAD]
    const float* __restrict__ data,   // [T][21][B]
    const float* __restrict__ x0,     // [NNEUR]
    const float* __restrict__ fcw,    // [NOUT][NPMAC]
    const float* __restrict__ fcb,    // [NOUT]
    float* __restrict__ out)          // [T][B][NOUT]
{
    __shared__ __align__(16) float Wl[NWAVE][LROWS][NPAD];   // 80 KB
    __shared__ __align__(16) float part[8][4][NPAD];         // 40 KB
    __shared__ __align__(16) float raug[MAUGP][4];           // 5.4 KB
    __shared__ __align__(16) float xs[4][NPAD];              // 5 KB
    __shared__ float fcwt[NPMAC][NOUT];                      // 20 KB
    __shared__ float fcbs[NOUT];

    const int tid = threadIdx.x;
    const int wid = tid >> 6;
    const int l   = tid & 63;
    const int b0  = blockIdx.x * 4;
    const int m0  = wid * MCHUNK;

    // ---- init: zero raug, load fc weights ----
    for (int i = tid; i < MAUGP * 4; i += 1024) ((float*)raug)[i] = 0.0f;
    for (int i = tid; i < NPMAC * NOUT; i += 1024) {
        int p = i / NOUT, o = i - p * NOUT;
        fcwt[p][o] = fcw[o * NPMAC + p];
    }
    if (tid < NOUT) fcbs[tid] = fcb[tid];
    __syncthreads();

    for (int i = tid; i < NNEUR; i += 1024) {
        float xv = x0[i];
        float rv = fmaxf(tanhf(xv), 0.0f);
        #pragma unroll
        for (int b = 0; b < 4; ++b) { xs[b][i] = xv; raug[i][b] = rv; }
    }
    if (tid < 4) raug[NNEUR + NFEAT + 1][tid] = 1.0f;   // const row

    // ---- resident rows m0+0..m0+1 (plain loads, demand < budget) ----
    const float* Wb = W + (size_t)m0 * NPAD;
    float4 wr0 = *reinterpret_cast<const float4*>(Wb + 4 * l);
    float  tr0 = Wb[256 + l];
    float4 wr1 = *reinterpret_cast<const float4*>(Wb + NPAD + 4 * l);
    float  tr1 = Wb[NPAD + 256 + l];

    // ---- LDS rows m0+2..m0+5 ----
    #pragma unroll
    for (int i = 0; i < LROWS; ++i) {
        *reinterpret_cast<float4*>(&Wl[wid][i][4 * l]) =
            *reinterpret_cast<const float4*>(&W[(size_t)(m0 + RES + i) * NPAD + 4 * l]);
        Wl[wid][i][256 + l] = W[(size_t)(m0 + RES + i) * NPAD + 256 + l];
    }

    // streamed region base: rows m0+6..m0+20
    const float* Ws = W + (size_t)(m0 + RES + LROWS) * NPAD;

    // prefetch data[t=0] slice (21 rows x 4 batch)
    float4 dstage = make_float4(0.f, 0.f, 0.f, 0.f);
    if (tid < NFEAT + 1)
        dstage = *reinterpret_cast<const float4*>(data + (size_t)tid * BATCH + b0);
    __syncthreads();

    for (int t = 0; t < TSTEPS; ++t) {
        // ---- Phase A: commit data[t], prefetch data[t+1] ----
        if (tid < NFEAT + 1) {
            *reinterpret_cast<float4*>(&raug[NNEUR + tid][0]) = dstage;
            if (t + 1 < TSTEPS)
                dstage = *reinterpret_cast<const float4*>(
                    data + ((size_t)(t + 1) * (NFEAT + 1) + tid) * BATCH + b0);
        }
        __syncthreads();

        // ---- Phase B: per-wave matvec over its 21-row m-chunk ----
        float a00 = 0.f, a01 = 0.f, a02 = 0.f, a03 = 0.f;
        float a10 = 0.f, a11 = 0.f, a12 = 0.f, a13 = 0.f;
        float a20 = 0.f, a21 = 0.f, a22 = 0.f, a23 = 0.f;
        float a30 = 0.f, a31 = 0.f, a32 = 0.f, a33 = 0.f;
        float t0 = 0.f, t1 = 0.f, t2 = 0.f, t3 = 0.f;

#define FMA_ROW(WV, WT, RIDX) { \
        const float4 rv_ = *reinterpret_cast<const float4*>(&raug[(RIDX)][0]); \
        a00 += WV.x * rv_.x; a01 += WV.x * rv_.y; a02 += WV.x * rv_.z; a03 += WV.x * rv_.w; \
        a10 += WV.y * rv_.x; a11 += WV.y * rv_.y; a12 += WV.y * rv_.z; a13 += WV.y * rv_.w; \
        a20 += WV.z * rv_.x; a21 += WV.z * rv_.y; a22 += WV.z * rv_.z; a23 += WV.z * rv_.w; \
        a30 += WV.w * rv_.x; a31 += WV.w * rv_.y; a32 += WV.w * rv_.z; a33 += WV.w * rv_.w; \
        t0  += (WT) * rv_.x; t1  += (WT) * rv_.y; t2  += (WT) * rv_.z; t3  += (WT) * rv_.w; }

        // issue first streamed load NOW; its latency hides under res+LDS FMAs
        float4 pa = *reinterpret_cast<const float4*>(Ws + 4 * l);
        float  ta = Ws[256 + l];
        float4 pb; float tb;

        // resident rows
        FMA_ROW(wr0, tr0, m0 + 0)
        FMA_ROW(wr1, tr1, m0 + 1)

        // LDS rows
        #pragma unroll
        for (int i = 0; i < LROWS; ++i) {
            const float4 wv_ = *reinterpret_cast<const float4*>(&Wl[wid][i][4 * l]);
            const float wlt  = Wl[wid][i][256 + l];
            FMA_ROW(wv_, wlt, m0 + RES + i)
        }

        // streamed rows, depth-1 pipeline with named double-buffer
#define STREAM_STEP(K, CUR4, CURT, NXT4, NXTT) { \
        if ((K) + 1 < STRM) { \
            const float* Wn_ = Ws + ((size_t)((K) + 1)) * NPAD; \
            NXT4 = *reinterpret_cast<const float4*>(Wn_ + 4 * l); \
            NXTT = Wn_[256 + l]; \
        } \
        FMA_ROW(CUR4, CURT, m0 + RES + LROWS + (K)) }

        STREAM_STEP(0,  pa, ta, pb, tb)
        STREAM_STEP(1,  pb, tb, pa, ta)
        STREAM_STEP(2,  pa, ta, pb, tb)
        STREAM_STEP(3,  pb, tb, pa, ta)
        STREAM_STEP(4,  pa, ta, pb, tb)
        STREAM_STEP(5,  pb, tb, pa, ta)
        STREAM_STEP(6,  pa, ta, pb, tb)
        STREAM_STEP(7,  pb, tb, pa, ta)
        STREAM_STEP(8,  pa, ta, pb, tb)
        STREAM_STEP(9,  pb, tb, pa, ta)
        STREAM_STEP(10, pa, ta, pb, tb)
        STREAM_STEP(11, pb, tb, pa, ta)
        STREAM_STEP(12, pa, ta, pb, tb)
        STREAM_STEP(13, pb, tb, pa, ta)
        STREAM_STEP(14, pa, ta, pb, tb)

        // ---- two-stage partial reduce: waves 0-7 write, 8-15 RMW-add ----
        if (wid < 8) {
            *reinterpret_cast<float4*>(&part[wid][0][4 * l]) = make_float4(a00, a10, a20, a30);
            part[wid][0][256 + l] = t0;
            *reinterpret_cast<float4*>(&part[wid][1][4 * l]) = make_float4(a01, a11, a21, a31);
            part[wid][1][256 + l] = t1;
            *reinterpret_cast<float4*>(&part[wid][2][4 * l]) = make_float4(a02, a12, a22, a32);
            part[wid][2][256 + l] = t2;
            *reinterpret_cast<float4*>(&part[wid][3][4 * l]) = make_float4(a03, a13, a23, a33);
            part[wid][3][256 + l] = t3;
        }
        __syncthreads();
        if (wid >= 8) {
            const int w8 = wid - 8;
            float4 p4;
            p4 = *reinterpret_cast<float4*>(&part[w8][0][4 * l]);
            p4.x += a00; p4.y += a10; p4.z += a20; p4.w += a30;
            *reinterpret_cast<float4*>(&part[w8][0][4 * l]) = p4;
            part[w8][0][256 + l] += t0;
            p4 = *reinterpret_cast<float4*>(&part[w8][1][4 * l]);
            p4.x += a01; p4.y += a11; p4.z += a21; p4.w += a31;
            *reinterpret_cast<float4*>(&part[w8][1][4 * l]) = p4;
            part[w8][1][256 + l] += t1;
            p4 = *reinterpret_cast<float4*>(&part[w8][2][4 * l]);
            p4.x += a02; p4.y += a12; p4.z += a22; p4.w += a32;
            *reinterpret_cast<float4*>(&part[w8][2][4 * l]) = p4;
            part[w8][2][256 + l] += t2;
            p4 = *reinterpret_cast<float4*>(&part[w8][3][4 * l]);
            p4.x += a03; p4.y += a13; p4.z += a23; p4.w += a33;
            *reinterpret_cast<float4*>(&part[w8][3][4 * l]) = p4;
            part[w8][3][256 + l] += t3;
        }
        __syncthreads();

        // ---- Phase C: reduce 8 partials, state update, write r ----
        {
            int b = tid / NPAD;
            int n = tid - b * NPAD;
            if (n < NNEUR) {
                float s = 0.0f;
                #pragma unroll
                for (int w8 = 0; w8 < 8; ++w8) s += part[w8][b][n];
                float xo  = xs[b][n];
                float pre = xo + (s - xo) * 0.1f;     // x + tdx/10
                xs[b][n] = pre;
                raug[n][b] = fmaxf(tanhf(pre), 0.0f);
            }
            if (tid < 256) {                           // items 1024..1279 -> b=3
                int n2 = 64 + tid;
                if (n2 < NNEUR) {
                    float s = 0.0f;
                    #pragma unroll
                    for (int w8 = 0; w8 < 8; ++w8) s += part[w8][3][n2];
                    float xo  = xs[3][n2];
                    float pre = xo + (s - xo) * 0.1f;
                    xs[3][n2] = pre;
                    raug[n2][3] = fmaxf(tanhf(pre), 0.0f);
                }
            }
        }
        __syncthreads();

        // ---- Phase D: y = r[:, :100] @ fcw.T + fcb, 4 threads per (b,o) ----
        if (tid < 800) {
            int pair = tid >> 2, seg = tid & 3;
            int b = pair / NOUT, o = pair - (pair / NOUT) * NOUT;
            int pb_ = seg * 25;
            float y = 0.0f;
            #pragma unroll 5
            for (int k = 0; k < 25; ++k)
                y += raug[pb_ + k][b] * fcwt[pb_ + k][o];
            y += __shfl_down(y, 1, 4);
            y += __shfl_down(y, 2, 4);
            if (seg == 0)
                out[((size_t)t * BATCH + b0 + b) * NOUT + o] = y + fcbs[o];
        }
        // no barrier: D reads raug rows <100; next A writes rows >=300; the
        // A-end barrier orders everything before the next part-write.
    }
}

extern "C" void kernel_launch(void* const* d_in, const int* in_sizes, int n_in,
                              void* d_out, int out_size, void* d_ws, size_t ws_size,
                              hipStream_t stream) {
    const float* data = (const float*)d_in[0];
    const float* J    = (const float*)d_in[1];
    const float* I    = (const float*)d_in[2];
    const float* S    = (const float*)d_in[3];
    const float* Bb   = (const float*)d_in[4];
    const float* x0   = (const float*)d_in[5];
    const float* fcw  = (const float*)d_in[6];
    const float* fcb  = (const float*)d_in[7];
    float* out = (float*)d_out;
    float* W   = (float*)d_ws;   // MAUGP*NPAD*4 = 430,080 bytes

    int wtot = MAUGP * NPAD;
    build_w_kernel<<<(wtot + 255) / 256, 256, 0, stream>>>(J, I, S, Bb, W);
    rnn_kernel<<<256, 1024, 0, stream>>>(W, data, x0, fcw, fcb, out);
}